// Round 8
// baseline (375.088 us; speedup 1.0000x reference)
//
#include <hip/hip_runtime.h>

// Native clang vector type — accepted by __builtin_nontemporal_load
typedef float vf4 __attribute__((ext_vector_type(4)));

// Workspace float offsets
#define WS_FPART 0      // fpart[4][128] (k_f partials, one per t; summed in k_h1)
#define WS_H1    640    // h1[450]
#define WS_FEAT  1152   // feat[450]
#define WS_H2    1664   // h2[450]

// K1: fpart[t][i] = sum_{p,c} x[4+t,p,c] * TwE[t,i] * PE[p,i] * CE[c,i]
// 256 blocks: each handles ONE t-slice (128 KB) for TWO outputs i — every
// x float2 load feeds 2 FMAs, halving both aggregate L2 traffic and
// per-block serial read vs R7's 512-block version.
__global__ __launch_bounds__(256) void k_f(
    const float* __restrict__ x, const float* __restrict__ TwE,
    const float* __restrict__ PE, const float* __restrict__ CE,
    float* __restrict__ fpart) {
  const int i0 = (blockIdx.x >> 2) * 2;    // first of the i-pair
  const int i1 = i0 + 1;
  const int t  = blockIdx.x & 3;
  const int tid = threadIdx.x;
  __shared__ float sCE0[128], sCE1[128];
  __shared__ float coef0[256], coef1[256]; // coef[p] = TwE[t,i] * PE[p,i]
  __shared__ float red[8];
  const float tw0 = TwE[t * 128 + i0];
  const float tw1 = TwE[t * 128 + i1];
  if (tid < 128) {
    sCE0[tid] = CE[tid * 128 + i0];
    sCE1[tid] = CE[tid * 128 + i1];
  }
  coef0[tid] = tw0 * PE[tid * 128 + i0];
  coef1[tid] = tw1 * PE[tid * 128 + i1];
  __syncthreads();
  const int lane = tid & 63;
  const int wv = tid >> 6;
  const float2 ce0 = ((const float2*)sCE0)[lane];
  const float2 ce1 = ((const float2*)sCE1)[lane];
  const float2* Xw = (const float2*)(x + 4 * 256 * 128);  // window start
  float acc0 = 0.f, acc1 = 0.f;
  const int l0 = wv * 64;                  // each wave: 64 of the 256 p-rows
#pragma unroll 8
  for (int k = 0; k < 64; ++k) {
    int l = l0 + k;                        // p index
    int q = (t << 8) + l;                  // global (t,p) row in window
    float2 v = Xw[q * 64 + lane];          // coalesced 512B wave load
    acc0 += coef0[l] * (v.x * ce0.x + v.y * ce0.y);
    acc1 += coef1[l] * (v.x * ce1.x + v.y * ce1.y);
  }
#pragma unroll
  for (int off = 32; off > 0; off >>= 1) {
    acc0 += __shfl_down(acc0, off);
    acc1 += __shfl_down(acc1, off);
  }
  if (lane == 0) { red[wv] = acc0; red[4 + wv] = acc1; }
  __syncthreads();
  if (tid == 0) fpart[t * 128 + i0] = red[0] + red[1] + red[2] + red[3];
  if (tid == 1) fpart[t * 128 + i1] = red[4] + red[5] + red[6] + red[7];
}

// K2+K3 merged: each block sums fpart -> f, redundantly computes feat0 = mE@f
// (thread-per-row, mE 230 KB/block through L1), then its 4 rows of
// h1 = relu(eW1@feat0 + eb1) wave-per-row.
__global__ __launch_bounds__(256) void k_h1(
    const float* __restrict__ fpart, const float* __restrict__ mE,
    const float* __restrict__ eW1, const float* __restrict__ eb1,
    float* __restrict__ h1) {
  __shared__ float sf[128];
  __shared__ float sfeat0[450];
  const int tid = threadIdx.x;
  if (tid < 128)
    sf[tid] = (fpart[tid] + fpart[128 + tid]) + (fpart[256 + tid] + fpart[384 + tid]);
  __syncthreads();
  for (int r = tid; r < 450; r += 256) {
    const float4* row = (const float4*)(mE + r * 128);  // 512B row, 16B-aligned
    float a0 = 0.f, a1 = 0.f, a2 = 0.f, a3 = 0.f;
#pragma unroll 8
    for (int k = 0; k < 32; ++k) {
      float4 m = row[k];
      a0 += m.x * sf[4 * k];      // LDS same-address across lanes: broadcast
      a1 += m.y * sf[4 * k + 1];
      a2 += m.z * sf[4 * k + 2];
      a3 += m.w * sf[4 * k + 3];
    }
    sfeat0[r] = (a0 + a1) + (a2 + a3);
  }
  __syncthreads();
  const int lane = tid & 63;
  const int row = blockIdx.x * 4 + (tid >> 6);
  if (row < 450) {
    const float2* Wr = (const float2*)(eW1 + row * 450);
    float acc = 0.f;
#pragma unroll
    for (int k = 0; k < 4; ++k) {
      int idx = lane + (k << 6);
      if (idx < 225) {
        float2 w = Wr[idx];
        acc += w.x * sfeat0[2 * idx] + w.y * sfeat0[2 * idx + 1];
      }
    }
#pragma unroll
    for (int off = 32; off > 0; off >>= 1) acc += __shfl_down(acc, off);
    if (lane == 0) h1[row] = fmaxf(acc + eb1[row], 0.f);
  }
}

// K4/K5: vout = [relu](W @ vin + b), W is 450x450. Wave per row.
__global__ __launch_bounds__(256) void k_mv450(
    const float* __restrict__ W, const float* __restrict__ b,
    const float* __restrict__ vin, float* __restrict__ vout, int relu) {
  __shared__ float sv[450];
  const int tid = threadIdx.x;
  if (tid < 450) sv[tid] = vin[tid];
  if (tid + 256 < 450) sv[tid + 256] = vin[tid + 256];
  __syncthreads();
  const int lane = tid & 63;
  const int row = blockIdx.x * 4 + (tid >> 6);
  if (row >= 450) return;
  const float2* Wr = (const float2*)(W + row * 450);
  float acc = 0.f;
#pragma unroll
  for (int k = 0; k < 4; ++k) {
    int idx = lane + (k << 6);
    if (idx < 225) {
      float2 w = Wr[idx];
      acc += w.x * sv[2 * idx] + w.y * sv[2 * idx + 1];
    }
  }
#pragma unroll
  for (int off = 32; off > 0; off >>= 1) acc += __shfl_down(acc, off);
  if (lane == 0) {
    float r = acc + b[row];
    if (relu) r = fmaxf(r, 0.f);
    vout[row] = r;
  }
}

// K6: out = dec_W2 @ h2 + dec_b2. Wave per ROW-PAIR (225 float4, 16B-aligned:
// pair stride 3600B). NT loads/stores (once-streamed 236 MB). 1024-thread
// blocks (16 pairs/block, 4096 blocks) halve the CP dispatch ramp vs R7.
__global__ __launch_bounds__(1024) void k_dec2(
    const float* __restrict__ W, const float* __restrict__ b,
    const float* __restrict__ h, float* __restrict__ out) {
  __shared__ float sv2[900];
  const int tid = threadIdx.x;
  if (tid < 900) sv2[tid] = h[tid < 450 ? tid : tid - 450];
  __syncthreads();
  const int lane = tid & 63;
  const int rp = blockIdx.x * 16 + (tid >> 6);   // row pair, 0..65535
  const vf4* Wp = (const vf4*)(W + (size_t)rp * 900);
  float accA = 0.f, accB = 0.f;
#pragma unroll
  for (int k = 0; k < 3; ++k) {
    int j = lane + (k << 6);          // 0..191
    vf4 w = __builtin_nontemporal_load(&Wp[j]);
    const float* s = &sv2[4 * j];
    float p01 = w.x * s[0] + w.y * s[1];
    float p23 = w.z * s[2] + w.w * s[3];
    if (4 * j + 3 < 450)      accA += p01 + p23;   // j <= 111
    else if (4 * j >= 450)    accB += p01 + p23;   // j >= 113
    else { accA += p01; accB += p23; }             // j == 112 straddles
  }
  if (lane < 33) {                    // j = 192..224, all row B
    int j = 192 + lane;
    vf4 w = __builtin_nontemporal_load(&Wp[j]);
    const float* s = &sv2[4 * j];
    accB += w.x * s[0] + w.y * s[1] + w.z * s[2] + w.w * s[3];
  }
#pragma unroll
  for (int off = 32; off > 0; off >>= 1) {
    accA += __shfl_down(accA, off);
    accB += __shfl_down(accB, off);
  }
  if (lane == 0) {
    int r = rp * 2;
    __builtin_nontemporal_store(accA + b[r],     &out[r]);
    __builtin_nontemporal_store(accB + b[r + 1], &out[r + 1]);
  }
}

extern "C" void kernel_launch(void* const* d_in, const int* in_sizes, int n_in,
                              void* d_out, int out_size, void* d_ws, size_t ws_size,
                              hipStream_t stream) {
  const float* x   = (const float*)d_in[0];
  const float* TwE = (const float*)d_in[2];
  const float* PE  = (const float*)d_in[3];
  const float* CE  = (const float*)d_in[4];
  const float* mE  = (const float*)d_in[5];
  const float* eW1 = (const float*)d_in[6];
  const float* eb1 = (const float*)d_in[7];
  const float* eW2 = (const float*)d_in[8];
  const float* eb2 = (const float*)d_in[9];
  const float* dW1 = (const float*)d_in[10];
  const float* db1 = (const float*)d_in[11];
  const float* dW2 = (const float*)d_in[12];
  const float* db2 = (const float*)d_in[13];
  float* out = (float*)d_out;
  float* ws  = (float*)d_ws;

  k_f    <<<256,  256,  0, stream>>>(x, TwE, PE, CE, ws + WS_FPART);
  k_h1   <<<113,  256,  0, stream>>>(ws + WS_FPART, mE, eW1, eb1, ws + WS_H1);
  k_mv450<<<113,  256,  0, stream>>>(eW2, eb2, ws + WS_H1, ws + WS_FEAT, 0);
  k_mv450<<<113,  256,  0, stream>>>(dW1, db1, ws + WS_FEAT, ws + WS_H2, 1);
  k_dec2 <<<4096, 1024, 0, stream>>>(dW2, db2, ws + WS_H2, out);
}

// Round 9
// 359.299 us; speedup vs baseline: 1.0439x; 1.0439x over previous
//
#include <hip/hip_runtime.h>

// Native clang vector type — accepted by __builtin_nontemporal_load
typedef float vf4 __attribute__((ext_vector_type(4)));

// Workspace float offsets
#define WS_FPART 0      // fpart[4][128] (k_f partials, one per t; summed in k_h1)
#define WS_H1    640    // h1[450]
#define WS_FEAT  1152   // feat[450]
#define WS_H2    1664   // h2[450]

// K1: fpart[t][i] = sum_{p,c} x[4+t,p,c] * TwE[t,i] * PE[p,i] * CE[c,i]
// 512 blocks = 4 per output i (one per t). Per-block L2-serial read = 128 KB.
// (R7-proven; R8's 2-outputs-per-block variant reverted.)
__global__ __launch_bounds__(256) void k_f(
    const float* __restrict__ x, const float* __restrict__ TwE,
    const float* __restrict__ PE, const float* __restrict__ CE,
    float* __restrict__ fpart) {
  const int i = blockIdx.x >> 2;
  const int t = blockIdx.x & 3;
  const int tid = threadIdx.x;
  __shared__ float sCE[128];
  __shared__ float coef[256];   // coef[p] = TwE[t,i] * PE[p,i]
  __shared__ float red[4];
  const float tw = TwE[t * 128 + i];     // wave-uniform scalar load
  if (tid < 128) sCE[tid] = CE[tid * 128 + i];
  coef[tid] = tw * PE[tid * 128 + i];
  __syncthreads();
  const int lane = tid & 63;
  const int wv = tid >> 6;
  const float2 ce = ((const float2*)sCE)[lane];
  const float2* Xw = (const float2*)(x + 4 * 256 * 128);  // window start
  float acc = 0.f;
  const int l0 = wv * 64;                // each wave: 64 of this block's 256 p-rows
#pragma unroll 8
  for (int k = 0; k < 64; ++k) {
    int l = l0 + k;                      // p index
    int q = (t << 8) + l;                // global (t,p) row in window
    float2 v = Xw[q * 64 + lane];        // coalesced 512B wave load
    acc += coef[l] * (v.x * ce.x + v.y * ce.y);
  }
#pragma unroll
  for (int off = 32; off > 0; off >>= 1) acc += __shfl_down(acc, off);
  if (lane == 0) red[wv] = acc;
  __syncthreads();
  if (tid == 0) fpart[t * 128 + i] = red[0] + red[1] + red[2] + red[3];
}

// K2+K3 merged: each block sums fpart -> f, redundantly computes feat0 = mE@f
// (thread-per-row, mE 230 KB/block through L1), then its 4 rows of
// h1 = relu(eW1@feat0 + eb1) wave-per-row.
__global__ __launch_bounds__(256) void k_h1(
    const float* __restrict__ fpart, const float* __restrict__ mE,
    const float* __restrict__ eW1, const float* __restrict__ eb1,
    float* __restrict__ h1) {
  __shared__ float sf[128];
  __shared__ float sfeat0[450];
  const int tid = threadIdx.x;
  if (tid < 128)
    sf[tid] = (fpart[tid] + fpart[128 + tid]) + (fpart[256 + tid] + fpart[384 + tid]);
  __syncthreads();
  for (int r = tid; r < 450; r += 256) {
    const float4* row = (const float4*)(mE + r * 128);  // 512B row, 16B-aligned
    float a0 = 0.f, a1 = 0.f, a2 = 0.f, a3 = 0.f;
#pragma unroll 8
    for (int k = 0; k < 32; ++k) {
      float4 m = row[k];
      a0 += m.x * sf[4 * k];      // LDS same-address across lanes: broadcast
      a1 += m.y * sf[4 * k + 1];
      a2 += m.z * sf[4 * k + 2];
      a3 += m.w * sf[4 * k + 3];
    }
    sfeat0[r] = (a0 + a1) + (a2 + a3);
  }
  __syncthreads();
  const int lane = tid & 63;
  const int row = blockIdx.x * 4 + (tid >> 6);
  if (row < 450) {
    const float2* Wr = (const float2*)(eW1 + row * 450);
    float acc = 0.f;
#pragma unroll
    for (int k = 0; k < 4; ++k) {
      int idx = lane + (k << 6);
      if (idx < 225) {
        float2 w = Wr[idx];
        acc += w.x * sfeat0[2 * idx] + w.y * sfeat0[2 * idx + 1];
      }
    }
#pragma unroll
    for (int off = 32; off > 0; off >>= 1) acc += __shfl_down(acc, off);
    if (lane == 0) h1[row] = fmaxf(acc + eb1[row], 0.f);
  }
}

// K4/K5: vout = [relu](W @ vin + b), W is 450x450. Wave per row.
__global__ __launch_bounds__(256) void k_mv450(
    const float* __restrict__ W, const float* __restrict__ b,
    const float* __restrict__ vin, float* __restrict__ vout, int relu) {
  __shared__ float sv[450];
  const int tid = threadIdx.x;
  if (tid < 450) sv[tid] = vin[tid];
  if (tid + 256 < 450) sv[tid + 256] = vin[tid + 256];
  __syncthreads();
  const int lane = tid & 63;
  const int row = blockIdx.x * 4 + (tid >> 6);
  if (row >= 450) return;
  const float2* Wr = (const float2*)(W + row * 450);
  float acc = 0.f;
#pragma unroll
  for (int k = 0; k < 4; ++k) {
    int idx = lane + (k << 6);
    if (idx < 225) {
      float2 w = Wr[idx];
      acc += w.x * sv[2 * idx] + w.y * sv[2 * idx + 1];
    }
  }
#pragma unroll
  for (int off = 32; off > 0; off >>= 1) acc += __shfl_down(acc, off);
  if (lane == 0) {
    float r = acc + b[row];
    if (relu) r = fmaxf(r, 0.f);
    vout[row] = r;
  }
}

// K6: out = dec_W2 @ h2 + dec_b2. Wave per ROW-PAIR (225 float4, 16B-aligned:
// pair stride 3600B). NT loads/stores (once-streamed 236 MB). 512-thread
// blocks (8 pairs/block, 8192 blocks): R7-proven sweet spot — 1024-thr (R8)
// regressed (16-wave block completion tail), 256-thr (R6) pays 2x dispatch ramp.
__global__ __launch_bounds__(512) void k_dec2(
    const float* __restrict__ W, const float* __restrict__ b,
    const float* __restrict__ h, float* __restrict__ out) {
  __shared__ float sv2[900];
  const int tid = threadIdx.x;
  for (int k = tid; k < 900; k += 512) sv2[k] = h[k < 450 ? k : k - 450];
  __syncthreads();
  const int lane = tid & 63;
  const int rp = blockIdx.x * 8 + (tid >> 6);    // row pair, 0..65535
  const vf4* Wp = (const vf4*)(W + (size_t)rp * 900);
  float accA = 0.f, accB = 0.f;
#pragma unroll
  for (int k = 0; k < 3; ++k) {
    int j = lane + (k << 6);          // 0..191
    vf4 w = __builtin_nontemporal_load(&Wp[j]);
    const float* s = &sv2[4 * j];
    float p01 = w.x * s[0] + w.y * s[1];
    float p23 = w.z * s[2] + w.w * s[3];
    if (4 * j + 3 < 450)      accA += p01 + p23;   // j <= 111
    else if (4 * j >= 450)    accB += p01 + p23;   // j >= 113
    else { accA += p01; accB += p23; }             // j == 112 straddles
  }
  if (lane < 33) {                    // j = 192..224, all row B
    int j = 192 + lane;
    vf4 w = __builtin_nontemporal_load(&Wp[j]);
    const float* s = &sv2[4 * j];
    accB += w.x * s[0] + w.y * s[1] + w.z * s[2] + w.w * s[3];
  }
#pragma unroll
  for (int off = 32; off > 0; off >>= 1) {
    accA += __shfl_down(accA, off);
    accB += __shfl_down(accB, off);
  }
  if (lane == 0) {
    int r = rp * 2;
    __builtin_nontemporal_store(accA + b[r],     &out[r]);
    __builtin_nontemporal_store(accB + b[r + 1], &out[r + 1]);
  }
}

extern "C" void kernel_launch(void* const* d_in, const int* in_sizes, int n_in,
                              void* d_out, int out_size, void* d_ws, size_t ws_size,
                              hipStream_t stream) {
  const float* x   = (const float*)d_in[0];
  const float* TwE = (const float*)d_in[2];
  const float* PE  = (const float*)d_in[3];
  const float* CE  = (const float*)d_in[4];
  const float* mE  = (const float*)d_in[5];
  const float* eW1 = (const float*)d_in[6];
  const float* eb1 = (const float*)d_in[7];
  const float* eW2 = (const float*)d_in[8];
  const float* eb2 = (const float*)d_in[9];
  const float* dW1 = (const float*)d_in[10];
  const float* db1 = (const float*)d_in[11];
  const float* dW2 = (const float*)d_in[12];
  const float* db2 = (const float*)d_in[13];
  float* out = (float*)d_out;
  float* ws  = (float*)d_ws;

  k_f    <<<512,  256, 0, stream>>>(x, TwE, PE, CE, ws + WS_FPART);
  k_h1   <<<113,  256, 0, stream>>>(ws + WS_FPART, mE, eW1, eb1, ws + WS_H1);
  k_mv450<<<113,  256, 0, stream>>>(eW2, eb2, ws + WS_H1, ws + WS_FEAT, 0);
  k_mv450<<<113,  256, 0, stream>>>(dW1, db1, ws + WS_FEAT, ws + WS_H2, 1);
  k_dec2 <<<8192, 512, 0, stream>>>(dW2, db2, ws + WS_H2, out);
}